// Round 1
// baseline (963.641 us; speedup 1.0000x reference)
//
#include <hip/hip_runtime.h>
#include <hip/hip_bf16.h>
#include <math.h>

// Problem constants (from reference)
#define TT   1024   // tokens
#define HH   1024   // hidden
#define II   512    // intermediate
#define EE   32     // routed experts
#define NE   40     // routed + zero experts
#define TOPK 4
#define CAP  1024   // max tokens per expert (<= T since top_k indices distinct)

// ---------------- workspace layout (bytes) ----------------
// counts:  int[EE]            @ 0        (zeroed each launch)
// topk_w:  float[TT*TOPK]     @ 1024
// zero_w:  float[TT]          @ 1024+16384
// slots:   int[EE*CAP]        @ 1024+16384+4096
// hmid:    float[TT*TOPK][II] @ 262144   (8 MB)
// total ~8.3 MB

// ============== Kernel 1: router (1 wave per token) ==============
__global__ __launch_bounds__(64) void router_kernel(
    const float* __restrict__ x, const float* __restrict__ rw,
    const float* __restrict__ bias,
    float* __restrict__ topk_w, float* __restrict__ zero_w,
    int* __restrict__ counts, int* __restrict__ slots)
{
    __shared__ float xs[HH];
    const int t = blockIdx.x;
    const int lane = threadIdx.x;

    // stage x[t] into LDS (float4)
    const float4* xp = (const float4*)(x + (size_t)t * HH);
    float4* xs4 = (float4*)xs;
    #pragma unroll
    for (int i = 0; i < HH / 4 / 64; ++i) xs4[lane + 64 * i] = xp[lane + 64 * i];
    __syncthreads();

    // logits: one expert at a time, coalesced rw reads + wave reduction
    float mylogit = -INFINITY;
    for (int e = 0; e < NE; ++e) {
        const float* r = rw + (size_t)e * HH;
        float p = 0.f;
        #pragma unroll
        for (int i = 0; i < HH / 64; ++i) {
            int h = lane + 64 * i;
            p += xs[h] * r[h];
        }
        #pragma unroll
        for (int off = 32; off > 0; off >>= 1) p += __shfl_xor(p, off);
        if (lane == e) mylogit = p;   // lane e holds logit_e
    }

    // softmax across lanes < NE
    float m = mylogit;
    #pragma unroll
    for (int off = 32; off > 0; off >>= 1) m = fmaxf(m, __shfl_xor(m, off));
    float pexp = (lane < NE) ? expf(mylogit - m) : 0.f;
    float s = pexp;
    #pragma unroll
    for (int off = 32; off > 0; off >>= 1) s += __shfl_xor(s, off);
    const float score = pexp / s;

    // top-4 on (score + bias); weight taken from UNBIASED score.
    float val = (lane < NE) ? score + bias[lane] : -INFINITY;
    int   kidx[TOPK];
    float kw[TOPK];
    #pragma unroll
    for (int k = 0; k < TOPK; ++k) {
        float v = val; int idx = lane;
        #pragma unroll
        for (int off = 32; off > 0; off >>= 1) {
            float ov = __shfl_xor(v, off);
            int   oi = __shfl_xor(idx, off);
            // max with tie -> lowest index (matches lax.top_k ordering)
            if (ov > v || (ov == v && oi < idx)) { v = ov; idx = oi; }
        }
        kidx[k] = idx;
        kw[k]   = __shfl(score, idx);
        if (lane == idx) val = -INFINITY;
    }

    if (lane == 0) {
        float zw = 0.f;
        #pragma unroll
        for (int k = 0; k < TOPK; ++k) {
            int slot = t * TOPK + k;
            topk_w[slot] = kw[k];
            if (kidx[k] < EE) {
                int pos = atomicAdd(&counts[kidx[k]], 1);
                slots[kidx[k] * CAP + pos] = slot;
            } else {
                zw += kw[k];   // zero-expert: identity with weight = score
            }
        }
        zero_w[t] = zw;
    }
}

// ============== Kernel 2: gate_up GEMM + SiLU (grouped by expert) ==============
// Tile: M=64 slots, 64 gate/up column-pairs (128 B-rows), K-tile 32.
#define TM 64
#define NP 64
#define KT 32

__global__ __launch_bounds__(256) void gate_up_kernel(
    const float* __restrict__ x, const float* __restrict__ wgu,
    const int* __restrict__ counts, const int* __restrict__ slots,
    float* __restrict__ hmid)
{
    const int e = blockIdx.x;
    const int cnt = counts[e];
    const int m_base = blockIdx.y * TM;
    if (m_base >= cnt) return;
    const int c_base = blockIdx.z * NP;

    __shared__ __align__(16) float As[TM][KT + 4];
    __shared__ __align__(16) float Bs[2 * NP][KT + 4];
    __shared__ int sl[TM];

    const int tid = threadIdx.x;
    if (tid < TM) {
        int m = m_base + tid;
        sl[tid] = (m < cnt) ? slots[e * CAP + m] : -1;
    }
    __syncthreads();

    const int tx = tid & 15;   // n-lane: n = tx + 16*j
    const int ty = tid >> 4;   // m-lane: m = ty + 16*i

    float accg[4][4] = {};
    float accu[4][4] = {};
    const float* wb = wgu + (size_t)e * (2 * II) * HH;

    for (int k0 = 0; k0 < HH; k0 += KT) {
        #pragma unroll
        for (int r = 0; r < (TM * KT) / 256; ++r) {       // 8
            int flat = tid + 256 * r;
            int mm = flat >> 5, kk = flat & 31;
            int slot = sl[mm];
            As[mm][kk] = (slot >= 0) ? x[(size_t)(slot >> 2) * HH + k0 + kk] : 0.f;
        }
        #pragma unroll
        for (int r = 0; r < (2 * NP * KT) / 256; ++r) {   // 16
            int flat = tid + 256 * r;
            int nn = flat >> 5, kk = flat & 31;
            int row = (nn < NP) ? (c_base + nn) : (II + c_base + (nn - NP));
            Bs[nn][kk] = wb[(size_t)row * HH + k0 + kk];
        }
        __syncthreads();

        #pragma unroll
        for (int kk = 0; kk < KT / 4; ++kk) {
            float4 a4[4], bg4[4], bu4[4];
            #pragma unroll
            for (int i = 0; i < 4; ++i) a4[i]  = *(const float4*)&As[ty + 16 * i][kk * 4];
            #pragma unroll
            for (int j = 0; j < 4; ++j) bg4[j] = *(const float4*)&Bs[tx + 16 * j][kk * 4];
            #pragma unroll
            for (int j = 0; j < 4; ++j) bu4[j] = *(const float4*)&Bs[NP + tx + 16 * j][kk * 4];
            #pragma unroll
            for (int i = 0; i < 4; ++i)
                #pragma unroll
                for (int j = 0; j < 4; ++j) {
                    accg[i][j] += a4[i].x * bg4[j].x + a4[i].y * bg4[j].y
                                + a4[i].z * bg4[j].z + a4[i].w * bg4[j].w;
                    accu[i][j] += a4[i].x * bu4[j].x + a4[i].y * bu4[j].y
                                + a4[i].z * bu4[j].z + a4[i].w * bu4[j].w;
                }
        }
        __syncthreads();
    }

    // epilogue: hmid[slot][c] = silu(gate)*up
    #pragma unroll
    for (int i = 0; i < 4; ++i) {
        int slot = sl[ty + 16 * i];
        if (slot < 0) continue;
        float* hrow = hmid + (size_t)slot * II + c_base;
        #pragma unroll
        for (int j = 0; j < 4; ++j) {
            float g = accg[i][j], u = accu[i][j];
            float sig = 1.f / (1.f + __expf(-g));
            hrow[tx + 16 * j] = g * sig * u;
        }
    }
}

// ============== Kernel 3: down GEMM + weighted scatter ==============
// Tile: M=64 slots, N=128 h-cols, K-tile 32 (K=512).
#define NB 128

__global__ __launch_bounds__(256) void down_kernel(
    const float* __restrict__ hmid, const float* __restrict__ wd,
    const int* __restrict__ counts, const int* __restrict__ slots,
    const float* __restrict__ topk_w, float* __restrict__ out)
{
    const int e = blockIdx.x;
    const int cnt = counts[e];
    const int m_base = blockIdx.y * TM;
    if (m_base >= cnt) return;
    const int n_base = blockIdx.z * NB;

    __shared__ __align__(16) float As[TM][KT + 4];
    __shared__ __align__(16) float Bs[NB][KT + 4];
    __shared__ int sl[TM];
    __shared__ float wv[TM];

    const int tid = threadIdx.x;
    if (tid < TM) {
        int m = m_base + tid;
        int slot = (m < cnt) ? slots[e * CAP + m] : -1;
        sl[tid] = slot;
        wv[tid] = (slot >= 0) ? topk_w[slot] : 0.f;
    }
    __syncthreads();

    const int tx = tid & 15;   // n = tx + 16*j, j<8
    const int ty = tid >> 4;   // m = ty + 16*i, i<4

    float acc[4][8] = {};
    const float* wb = wd + (size_t)e * HH * II;

    for (int k0 = 0; k0 < II; k0 += KT) {
        #pragma unroll
        for (int r = 0; r < (TM * KT) / 256; ++r) {
            int flat = tid + 256 * r;
            int mm = flat >> 5, kk = flat & 31;
            int slot = sl[mm];
            As[mm][kk] = (slot >= 0) ? hmid[(size_t)slot * II + k0 + kk] : 0.f;
        }
        #pragma unroll
        for (int r = 0; r < (NB * KT) / 256; ++r) {
            int flat = tid + 256 * r;
            int nn = flat >> 5, kk = flat & 31;
            Bs[nn][kk] = wb[(size_t)(n_base + nn) * II + k0 + kk];
        }
        __syncthreads();

        #pragma unroll
        for (int kk = 0; kk < KT / 4; ++kk) {
            float4 a4[4], b4[8];
            #pragma unroll
            for (int i = 0; i < 4; ++i) a4[i] = *(const float4*)&As[ty + 16 * i][kk * 4];
            #pragma unroll
            for (int j = 0; j < 8; ++j) b4[j] = *(const float4*)&Bs[tx + 16 * j][kk * 4];
            #pragma unroll
            for (int i = 0; i < 4; ++i)
                #pragma unroll
                for (int j = 0; j < 8; ++j)
                    acc[i][j] += a4[i].x * b4[j].x + a4[i].y * b4[j].y
                               + a4[i].z * b4[j].z + a4[i].w * b4[j].w;
        }
        __syncthreads();
    }

    #pragma unroll
    for (int i = 0; i < 4; ++i) {
        int slot = sl[ty + 16 * i];
        if (slot < 0) continue;
        float w = wv[ty + 16 * i];
        float* orow = out + (size_t)(slot >> 2) * HH + n_base;
        #pragma unroll
        for (int j = 0; j < 8; ++j)
            atomicAdd(&orow[tx + 16 * j], w * acc[i][j]);
    }
}

// ============== Kernel 4: zero-expert identity residual ==============
__global__ __launch_bounds__(256) void zero_resid_kernel(
    const float* __restrict__ x, const float* __restrict__ zero_w,
    float* __restrict__ out)
{
    const int t = blockIdx.x;
    const float zw = zero_w[t];
    const int tid = threadIdx.x;
    const float4 xv = ((const float4*)(x + (size_t)t * HH))[tid];
    float4* o = (float4*)(out + (size_t)t * HH);
    float4 ov = o[tid];
    ov.x += zw * xv.x; ov.y += zw * xv.y; ov.z += zw * xv.z; ov.w += zw * xv.w;
    o[tid] = ov;
}

extern "C" void kernel_launch(void* const* d_in, const int* in_sizes, int n_in,
                              void* d_out, int out_size, void* d_ws, size_t ws_size,
                              hipStream_t stream) {
    const float* x    = (const float*)d_in[0];   // [T,H]
    const float* rw   = (const float*)d_in[1];   // [E+Z,H]
    const float* bias = (const float*)d_in[2];   // [E+Z]
    const float* wgu  = (const float*)d_in[3];   // [E,2I,H]
    const float* wd   = (const float*)d_in[4];   // [E,H,I]
    // d_in[5] = top_k (==4, hardcoded)
    float* out = (float*)d_out;

    char* ws = (char*)d_ws;
    int*   counts = (int*)ws;
    float* topk_w = (float*)(ws + 1024);
    float* zero_w = (float*)(ws + 1024 + 16384);
    int*   slots  = (int*)(ws + 1024 + 16384 + 4096);
    float* hmid   = (float*)(ws + 262144);

    hipMemsetAsync(counts, 0, EE * sizeof(int), stream);
    hipMemsetAsync(out, 0, (size_t)out_size * sizeof(float), stream);

    router_kernel<<<dim3(TT), dim3(64), 0, stream>>>(x, rw, bias, topk_w, zero_w, counts, slots);
    gate_up_kernel<<<dim3(EE, CAP / TM, II / NP), dim3(256), 0, stream>>>(x, wgu, counts, slots, hmid);
    down_kernel<<<dim3(EE, CAP / TM, HH / NB), dim3(256), 0, stream>>>(hmid, wd, counts, slots, topk_w, out);
    zero_resid_kernel<<<dim3(TT), dim3(256), 0, stream>>>(x, zero_w, out);
}

// Round 2
// 408.842 us; speedup vs baseline: 2.3570x; 2.3570x over previous
//
#include <hip/hip_runtime.h>
#include <hip/hip_bf16.h>
#include <math.h>

// Problem constants (from reference)
#define TT   1024   // tokens
#define HH   1024   // hidden
#define II   512    // intermediate
#define EE   32     // routed experts
#define NE   40     // routed + zero experts
#define TOPK 4
#define CAP  1024   // max tokens per expert

typedef __attribute__((ext_vector_type(4))) short short4v;
typedef __attribute__((ext_vector_type(8))) short short8v;
typedef __attribute__((ext_vector_type(4))) float floatx4;

// fp32 -> bf16 bits, round-to-nearest-even
static __device__ __forceinline__ short f2bf(float f) {
    unsigned u = __float_as_uint(f);
    unsigned r = (u + 0x7fffu + ((u >> 16) & 1u)) >> 16;
    return (short)(r & 0xffffu);
}

// ---------------- workspace layout (bytes) ----------------
// counts:  int[EE]            @ 0        (zeroed each launch)
// topk_w:  float[TT*TOPK]     @ 1024
// zero_w:  float[TT]          @ 1024+16384
// slots:   int[EE*CAP]        @ 1024+16384+4096
// hmid:    bf16[TT*TOPK][II]  @ 262144   (4 MB)

// ============== Kernel 1: router (1 wave per token) ==============
__global__ __launch_bounds__(64) void router_kernel(
    const float* __restrict__ x, const float* __restrict__ rw,
    const float* __restrict__ bias,
    float* __restrict__ topk_w, float* __restrict__ zero_w,
    int* __restrict__ counts, int* __restrict__ slots)
{
    __shared__ float xs[HH];
    const int t = blockIdx.x;
    const int lane = threadIdx.x;

    const float4* xp = (const float4*)(x + (size_t)t * HH);
    float4* xs4 = (float4*)xs;
    #pragma unroll
    for (int i = 0; i < HH / 4 / 64; ++i) xs4[lane + 64 * i] = xp[lane + 64 * i];
    __syncthreads();

    float mylogit = -INFINITY;
    for (int e = 0; e < NE; ++e) {
        const float* r = rw + (size_t)e * HH;
        float p = 0.f;
        #pragma unroll
        for (int i = 0; i < HH / 64; ++i) {
            int h = lane + 64 * i;
            p += xs[h] * r[h];
        }
        #pragma unroll
        for (int off = 32; off > 0; off >>= 1) p += __shfl_xor(p, off);
        if (lane == e) mylogit = p;
    }

    float m = mylogit;
    #pragma unroll
    for (int off = 32; off > 0; off >>= 1) m = fmaxf(m, __shfl_xor(m, off));
    float pexp = (lane < NE) ? expf(mylogit - m) : 0.f;
    float s = pexp;
    #pragma unroll
    for (int off = 32; off > 0; off >>= 1) s += __shfl_xor(s, off);
    const float score = pexp / s;

    float val = (lane < NE) ? score + bias[lane] : -INFINITY;
    int   kidx[TOPK];
    float kw[TOPK];
    #pragma unroll
    for (int k = 0; k < TOPK; ++k) {
        float v = val; int idx = lane;
        #pragma unroll
        for (int off = 32; off > 0; off >>= 1) {
            float ov = __shfl_xor(v, off);
            int   oi = __shfl_xor(idx, off);
            if (ov > v || (ov == v && oi < idx)) { v = ov; idx = oi; }
        }
        kidx[k] = idx;
        kw[k]   = __shfl(score, idx);
        if (lane == idx) val = -INFINITY;
    }

    if (lane == 0) {
        float zw = 0.f;
        #pragma unroll
        for (int k = 0; k < TOPK; ++k) {
            int slot = t * TOPK + k;
            topk_w[slot] = kw[k];
            if (kidx[k] < EE) {
                int pos = atomicAdd(&counts[kidx[k]], 1);
                slots[kidx[k] * CAP + pos] = slot;
            } else {
                zw += kw[k];
            }
        }
        zero_w[t] = zw;
    }
}

// ============== Kernel 2: gate_up bf16 MFMA GEMM + SiLU ==============
// Tile: M=128 slots, 64 gate/up col-pairs (128 B-rows), K-slab 32.
// 4 waves as 2x2: wy -> 64-row m-half, wx -> 32-pair n-half.
#define GM 128
#define GN 64
#define GK 32
#define KP 40   // LDS pitch in bf16 elems: 80 B, 16B-aligned, 2-way banks (free)

__global__ __launch_bounds__(256) void gate_up_kernel(
    const float* __restrict__ x, const float* __restrict__ wgu,
    const int* __restrict__ counts, const int* __restrict__ slots,
    short* __restrict__ hmid)
{
    const int e = blockIdx.x;
    const int cnt = counts[e];
    const int m_base = blockIdx.y * GM;
    if (m_base >= cnt) return;
    const int c_base = blockIdx.z * GN;

    __shared__ short As[GM * KP];
    __shared__ short Bs[2 * GN * KP];
    __shared__ int   sl[GM];

    const int tid = threadIdx.x;
    if (tid < GM) {
        int m = m_base + tid;
        sl[tid] = (m < cnt) ? slots[e * CAP + m] : -1;
    }
    __syncthreads();

    const int lane = tid & 63;
    const int wv_  = tid >> 6;
    const int wy   = wv_ & 1;      // m-half
    const int wx   = wv_ >> 1;     // n-half
    const int quad = lane >> 4;
    const int mcol = lane & 15;

    floatx4 accg[4][2] = {};
    floatx4 accu[4][2] = {};
    const float* wb = wgu + (size_t)e * (2 * II) * HH;

    for (int k0 = 0; k0 < HH; k0 += GK) {
        // ---- stage A (128x32 fp32 -> bf16), coalesced float4 ----
        #pragma unroll
        for (int it = 0; it < 4; ++it) {
            int f = tid + 256 * it;          // float4 id, 1024 total
            int row = f >> 3, kq = f & 7;
            int s = sl[row];
            float4 v = make_float4(0.f, 0.f, 0.f, 0.f);
            if (s >= 0) v = *(const float4*)&x[(size_t)(s >> 2) * HH + k0 + kq * 4];
            short4v b = { f2bf(v.x), f2bf(v.y), f2bf(v.z), f2bf(v.w) };
            *(short4v*)&As[row * KP + kq * 4] = b;
        }
        // ---- stage B (128 rows: 64 gate then 64 up) ----
        #pragma unroll
        for (int it = 0; it < 4; ++it) {
            int f = tid + 256 * it;
            int row = f >> 3, kq = f & 7;
            int grow = (row < GN) ? (c_base + row) : (II + c_base + row - GN);
            float4 v = *(const float4*)&wb[(size_t)grow * HH + k0 + kq * 4];
            short4v b = { f2bf(v.x), f2bf(v.y), f2bf(v.z), f2bf(v.w) };
            *(short4v*)&Bs[row * KP + kq * 4] = b;
        }
        __syncthreads();

        short8v a[4], bg[2], bu[2];
        #pragma unroll
        for (int i = 0; i < 4; ++i)
            a[i] = *(const short8v*)&As[(wy * 64 + i * 16 + mcol) * KP + quad * 8];
        #pragma unroll
        for (int j = 0; j < 2; ++j) {
            bg[j] = *(const short8v*)&Bs[(wx * 32 + j * 16 + mcol) * KP + quad * 8];
            bu[j] = *(const short8v*)&Bs[(GN + wx * 32 + j * 16 + mcol) * KP + quad * 8];
        }
        #pragma unroll
        for (int i = 0; i < 4; ++i)
            #pragma unroll
            for (int j = 0; j < 2; ++j) {
                accg[i][j] = __builtin_amdgcn_mfma_f32_16x16x32_bf16(a[i], bg[j], accg[i][j], 0, 0, 0);
                accu[i][j] = __builtin_amdgcn_mfma_f32_16x16x32_bf16(a[i], bu[j], accu[i][j], 0, 0, 0);
            }
        __syncthreads();
    }

    // epilogue: hmid[slot][c] = silu(gate)*up   (C/D: col=lane&15, row=quad*4+reg)
    #pragma unroll
    for (int i = 0; i < 4; ++i) {
        #pragma unroll
        for (int r = 0; r < 4; ++r) {
            int m = wy * 64 + i * 16 + quad * 4 + r;
            int s = sl[m];
            if (s < 0) continue;
            short* hrow = hmid + (size_t)s * II + c_base + wx * 32;
            #pragma unroll
            for (int j = 0; j < 2; ++j) {
                float g = accg[i][j][r], u = accu[i][j][r];
                float valf = g * u / (1.f + __expf(-g));
                hrow[j * 16 + mcol] = f2bf(valf);
            }
        }
    }
}

// ============== Kernel 3: down bf16 MFMA GEMM + weighted scatter ==============
// Tile: M=128 slots, N=128 h-cols, K=512 in slabs of 32. Waves 2x2 (64x64 each).
#define DM 128
#define DN 128

__global__ __launch_bounds__(256) void down_kernel(
    const short* __restrict__ hmid, const float* __restrict__ wd,
    const int* __restrict__ counts, const int* __restrict__ slots,
    const float* __restrict__ topk_w, float* __restrict__ out)
{
    const int e = blockIdx.x;
    const int cnt = counts[e];
    const int m_base = blockIdx.y * DM;
    if (m_base >= cnt) return;
    const int n_base = blockIdx.z * DN;

    __shared__ short As[DM * KP];
    __shared__ short Bs[DN * KP];
    __shared__ int   sl[DM];
    __shared__ float wvs[DM];

    const int tid = threadIdx.x;
    if (tid < DM) {
        int m = m_base + tid;
        int s = (m < cnt) ? slots[e * CAP + m] : -1;
        sl[tid] = s;
        wvs[tid] = (s >= 0) ? topk_w[s] : 0.f;
    }
    __syncthreads();

    const int lane = tid & 63;
    const int wv_  = tid >> 6;
    const int wy   = wv_ & 1;
    const int wx   = wv_ >> 1;
    const int quad = lane >> 4;
    const int mcol = lane & 15;

    floatx4 acc[4][4] = {};
    const float* wb = wd + (size_t)e * HH * II;

    for (int k0 = 0; k0 < II; k0 += GK) {
        // ---- stage A from bf16 hmid (gathered rows), coalesced short4 ----
        #pragma unroll
        for (int it = 0; it < 4; ++it) {
            int f = tid + 256 * it;          // short4 id, 1024 total
            int row = f >> 3, kq = f & 7;
            int s = sl[row];
            short4v v = { 0, 0, 0, 0 };
            if (s >= 0) v = *(const short4v*)&hmid[(size_t)s * II + k0 + kq * 4];
            *(short4v*)&As[row * KP + kq * 4] = v;
        }
        // ---- stage B (fp32 -> bf16) ----
        #pragma unroll
        for (int it = 0; it < 4; ++it) {
            int f = tid + 256 * it;
            int row = f >> 3, kq = f & 7;
            float4 v = *(const float4*)&wb[(size_t)(n_base + row) * II + k0 + kq * 4];
            short4v b = { f2bf(v.x), f2bf(v.y), f2bf(v.z), f2bf(v.w) };
            *(short4v*)&Bs[row * KP + kq * 4] = b;
        }
        __syncthreads();

        short8v a[4], b[4];
        #pragma unroll
        for (int i = 0; i < 4; ++i)
            a[i] = *(const short8v*)&As[(wy * 64 + i * 16 + mcol) * KP + quad * 8];
        #pragma unroll
        for (int j = 0; j < 4; ++j)
            b[j] = *(const short8v*)&Bs[(wx * 64 + j * 16 + mcol) * KP + quad * 8];
        #pragma unroll
        for (int i = 0; i < 4; ++i)
            #pragma unroll
            for (int j = 0; j < 4; ++j)
                acc[i][j] = __builtin_amdgcn_mfma_f32_16x16x32_bf16(a[i], b[j], acc[i][j], 0, 0, 0);
        __syncthreads();
    }

    #pragma unroll
    for (int i = 0; i < 4; ++i) {
        #pragma unroll
        for (int r = 0; r < 4; ++r) {
            int m = wy * 64 + i * 16 + quad * 4 + r;
            int s = sl[m];
            if (s < 0) continue;
            float wrt = wvs[m];
            float* orow = out + (size_t)(s >> 2) * HH + n_base + wx * 64;
            #pragma unroll
            for (int j = 0; j < 4; ++j)
                atomicAdd(&orow[j * 16 + mcol], wrt * acc[i][j][r]);
        }
    }
}

// ============== Kernel 4: zero-expert identity residual ==============
__global__ __launch_bounds__(256) void zero_resid_kernel(
    const float* __restrict__ x, const float* __restrict__ zero_w,
    float* __restrict__ out)
{
    const int t = blockIdx.x;
    const float zw = zero_w[t];
    const int tid = threadIdx.x;
    const float4 xv = ((const float4*)(x + (size_t)t * HH))[tid];
    float4* o = (float4*)(out + (size_t)t * HH);
    float4 ov = o[tid];
    ov.x += zw * xv.x; ov.y += zw * xv.y; ov.z += zw * xv.z; ov.w += zw * xv.w;
    o[tid] = ov;
}

extern "C" void kernel_launch(void* const* d_in, const int* in_sizes, int n_in,
                              void* d_out, int out_size, void* d_ws, size_t ws_size,
                              hipStream_t stream) {
    const float* x    = (const float*)d_in[0];   // [T,H]
    const float* rw   = (const float*)d_in[1];   // [E+Z,H]
    const float* bias = (const float*)d_in[2];   // [E+Z]
    const float* wgu  = (const float*)d_in[3];   // [E,2I,H]
    const float* wd   = (const float*)d_in[4];   // [E,H,I]
    float* out = (float*)d_out;

    char* ws = (char*)d_ws;
    int*   counts = (int*)ws;
    float* topk_w = (float*)(ws + 1024);
    float* zero_w = (float*)(ws + 1024 + 16384);
    int*   slots  = (int*)(ws + 1024 + 16384 + 4096);
    short* hmid   = (short*)(ws + 262144);

    hipMemsetAsync(counts, 0, EE * sizeof(int), stream);
    hipMemsetAsync(out, 0, (size_t)out_size * sizeof(float), stream);

    router_kernel<<<dim3(TT), dim3(64), 0, stream>>>(x, rw, bias, topk_w, zero_w, counts, slots);
    gate_up_kernel<<<dim3(EE, CAP / GM, II / GN), dim3(256), 0, stream>>>(x, wgu, counts, slots, hmid);
    down_kernel<<<dim3(EE, CAP / DM, HH / DN), dim3(256), 0, stream>>>(hmid, wd, counts, slots, topk_w, out);
    zero_resid_kernel<<<dim3(TT), dim3(256), 0, stream>>>(x, zero_w, out);
}

// Round 3
// 313.891 us; speedup vs baseline: 3.0700x; 1.3025x over previous
//
#include <hip/hip_runtime.h>
#include <hip/hip_bf16.h>
#include <math.h>

#define TT   1024
#define HH   1024
#define II   512
#define EE   32
#define NE   40
#define TOPK 4
#define CAP  1024

typedef __attribute__((ext_vector_type(4))) short short4v;
typedef __attribute__((ext_vector_type(8))) short short8v;
typedef __attribute__((ext_vector_type(4))) float floatx4;

static __device__ __forceinline__ short f2bf(float f) {
    unsigned u = __float_as_uint(f);
    unsigned r = (u + 0x7fffu + ((u >> 16) & 1u)) >> 16;
    return (short)(r & 0xffffu);
}
static __device__ __forceinline__ float bf2f(short s) {
    return __uint_as_float(((unsigned)(unsigned short)s) << 16);
}
static __device__ __forceinline__ short4v cvt4(float4 v) {
    short4v b = { f2bf(v.x), f2bf(v.y), f2bf(v.z), f2bf(v.w) };
    return b;
}

// ---------------- workspace layout (bytes) ----------------
// counts: int[EE]           @ 0
// topk_w: float[TT*TOPK]    @ 1024
// zero_w: float[TT]         @ 17408
// kexp:   int[TT*TOPK]      @ 21504
// slots:  int[EE*CAP]       @ 40960
// hmid:   bf16[TT*TOPK*II]  @ 262144    (4 MB)
// ydown:  bf16[TT*TOPK*HH]  @ 4456448   (8 MB)  [combine path only]
#define WS_NEED_COMBINE 12845056ull

// ============== Kernel 1: router (1 wave/token, 4-expert unroll) ==============
__global__ __launch_bounds__(64) void router_kernel(
    const float* __restrict__ x, const float* __restrict__ rw,
    const float* __restrict__ bias,
    float* __restrict__ topk_w, float* __restrict__ zero_w,
    int* __restrict__ kexp, int* __restrict__ counts, int* __restrict__ slots)
{
    __shared__ float xs[HH];
    const int t = blockIdx.x;
    const int lane = threadIdx.x;

    const float4* xp = (const float4*)(x + (size_t)t * HH);
    float4* xs4 = (float4*)xs;
    #pragma unroll
    for (int i = 0; i < HH / 4 / 64; ++i) xs4[lane + 64 * i] = xp[lane + 64 * i];
    __syncthreads();

    float mylogit = -INFINITY;
    for (int e0 = 0; e0 < NE; e0 += 4) {
        const float* r0 = rw + (size_t)e0 * HH;
        float p0 = 0.f, p1 = 0.f, p2 = 0.f, p3 = 0.f;
        #pragma unroll
        for (int i = 0; i < HH / 64; ++i) {
            int h = lane + 64 * i;
            float xv = xs[h];
            p0 += xv * r0[h];
            p1 += xv * r0[HH + h];
            p2 += xv * r0[2 * HH + h];
            p3 += xv * r0[3 * HH + h];
        }
        #pragma unroll
        for (int off = 32; off > 0; off >>= 1) {
            p0 += __shfl_xor(p0, off); p1 += __shfl_xor(p1, off);
            p2 += __shfl_xor(p2, off); p3 += __shfl_xor(p3, off);
        }
        if (lane == e0)     mylogit = p0;
        if (lane == e0 + 1) mylogit = p1;
        if (lane == e0 + 2) mylogit = p2;
        if (lane == e0 + 3) mylogit = p3;
    }

    float m = mylogit;
    #pragma unroll
    for (int off = 32; off > 0; off >>= 1) m = fmaxf(m, __shfl_xor(m, off));
    float pexp = (lane < NE) ? expf(mylogit - m) : 0.f;
    float s = pexp;
    #pragma unroll
    for (int off = 32; off > 0; off >>= 1) s += __shfl_xor(s, off);
    const float score = pexp / s;

    float val = (lane < NE) ? score + bias[lane] : -INFINITY;
    int   kidx[TOPK];
    float kw[TOPK];
    #pragma unroll
    for (int k = 0; k < TOPK; ++k) {
        float v = val; int idx = lane;
        #pragma unroll
        for (int off = 32; off > 0; off >>= 1) {
            float ov = __shfl_xor(v, off);
            int   oi = __shfl_xor(idx, off);
            if (ov > v || (ov == v && oi < idx)) { v = ov; idx = oi; }
        }
        kidx[k] = idx;
        kw[k]   = __shfl(score, idx);
        if (lane == idx) val = -INFINITY;
    }

    if (lane == 0) {
        float zw = 0.f;
        #pragma unroll
        for (int k = 0; k < TOPK; ++k) {
            int slot = t * TOPK + k;
            topk_w[slot] = kw[k];
            kexp[slot]   = kidx[k];
            if (kidx[k] < EE) {
                int pos = atomicAdd(&counts[kidx[k]], 1);
                slots[kidx[k] * CAP + pos] = slot;
            } else {
                zw += kw[k];
            }
        }
        zero_w[t] = zw;
    }
}

// ============== Kernel 2: gate_up bf16 MFMA GEMM + SiLU ==============
// grid: x = n-slab (always active, spreads over CUs), y = expert, z = m-tile
#define GM  128
#define GNP 32     // gate/up pairs per block -> 64 B rows
#define GK  32
#define KP  40     // LDS pitch (bf16 elems)

__global__ __launch_bounds__(256) void gate_up_kernel(
    const float* __restrict__ x, const float* __restrict__ wgu,
    const int* __restrict__ counts, const int* __restrict__ slots,
    short* __restrict__ hmid)
{
    const int e = blockIdx.y;
    const int cnt = counts[e];
    const int m_base = blockIdx.z * GM;
    if (m_base >= cnt) return;
    const int c_base = blockIdx.x * GNP;

    __shared__ short As[2][GM * KP];
    __shared__ short Bs[2][2 * GNP * KP];
    __shared__ int   sl[GM];

    const int tid = threadIdx.x;
    if (tid < GM) {
        int m = m_base + tid;
        sl[tid] = (m < cnt) ? slots[e * CAP + m] : -1;
    }
    __syncthreads();

    const int kq = tid & 7;
    const float* wb = wgu + (size_t)e * (2 * II) * HH;

    // precompute staging rows/pointers (no per-iter LDS dependency)
    int rowA[4]; int slA[4]; const float* pAx[4];
    #pragma unroll
    for (int it = 0; it < 4; ++it) {
        rowA[it] = (tid >> 3) + 32 * it;
        int s = sl[rowA[it]];
        slA[it] = s;
        pAx[it] = x + (size_t)((s >= 0 ? s : 0) >> 2) * HH + kq * 4;
    }
    int rowB[2]; const float* pB[2];
    #pragma unroll
    for (int it = 0; it < 2; ++it) {
        rowB[it] = (tid >> 3) + 32 * it;
        int grow = (rowB[it] < GNP) ? (c_base + rowB[it]) : (II + c_base + rowB[it] - GNP);
        pB[it] = wb + (size_t)grow * HH + kq * 4;
    }

    const int lane = tid & 63;
    const int wv_  = tid >> 6;
    const int wy   = wv_ & 1;
    const int wx   = wv_ >> 1;
    const int quad = lane >> 4;
    const int mcol = lane & 15;

    floatx4 accg[4] = {};
    floatx4 accu[4] = {};

    float4 pa[4], pb[2];
    const float4 fz = make_float4(0.f, 0.f, 0.f, 0.f);

    // prologue: load + store slab 0
    #pragma unroll
    for (int it = 0; it < 4; ++it) pa[it] = (slA[it] >= 0) ? *(const float4*)(pAx[it]) : fz;
    #pragma unroll
    for (int it = 0; it < 2; ++it) pb[it] = *(const float4*)(pB[it]);
    #pragma unroll
    for (int it = 0; it < 4; ++it) *(short4v*)&As[0][rowA[it] * KP + kq * 4] = cvt4(pa[it]);
    #pragma unroll
    for (int it = 0; it < 2; ++it) *(short4v*)&Bs[0][rowB[it] * KP + kq * 4] = cvt4(pb[it]);
    __syncthreads();

    int p = 0;
    for (int k0 = 0; k0 < HH; k0 += GK) {
        const int kn = k0 + GK;
        const bool more = kn < HH;
        if (more) {
            #pragma unroll
            for (int it = 0; it < 4; ++it) pa[it] = (slA[it] >= 0) ? *(const float4*)(pAx[it] + kn) : fz;
            #pragma unroll
            for (int it = 0; it < 2; ++it) pb[it] = *(const float4*)(pB[it] + kn);
        }

        short8v a[4], bg, bu;
        #pragma unroll
        for (int i = 0; i < 4; ++i)
            a[i] = *(const short8v*)&As[p][(wy * 64 + i * 16 + mcol) * KP + quad * 8];
        bg = *(const short8v*)&Bs[p][(wx * 16 + mcol) * KP + quad * 8];
        bu = *(const short8v*)&Bs[p][(GNP + wx * 16 + mcol) * KP + quad * 8];
        #pragma unroll
        for (int i = 0; i < 4; ++i) {
            accg[i] = __builtin_amdgcn_mfma_f32_16x16x32_bf16(a[i], bg, accg[i], 0, 0, 0);
            accu[i] = __builtin_amdgcn_mfma_f32_16x16x32_bf16(a[i], bu, accu[i], 0, 0, 0);
        }

        if (more) {
            #pragma unroll
            for (int it = 0; it < 4; ++it) *(short4v*)&As[1 - p][rowA[it] * KP + kq * 4] = cvt4(pa[it]);
            #pragma unroll
            for (int it = 0; it < 2; ++it) *(short4v*)&Bs[1 - p][rowB[it] * KP + kq * 4] = cvt4(pb[it]);
        }
        __syncthreads();
        p ^= 1;
    }

    // epilogue: hmid[slot][c] = silu(gate)*up
    #pragma unroll
    for (int i = 0; i < 4; ++i) {
        #pragma unroll
        for (int r = 0; r < 4; ++r) {
            int m = wy * 64 + i * 16 + quad * 4 + r;
            int s = sl[m];
            if (s < 0) continue;
            float g = accg[i][r], u = accu[i][r];
            float valf = g * u / (1.f + __expf(-g));
            hmid[(size_t)s * II + c_base + wx * 16 + mcol] = f2bf(valf);
        }
    }
}

// ============== Kernel 3: down bf16 MFMA GEMM ==============
#define DM 128
#define DN 64

template<int WRITE_Y>
__global__ __launch_bounds__(256) void down_kernel_t(
    const short* __restrict__ hmid, const float* __restrict__ wd,
    const int* __restrict__ counts, const int* __restrict__ slots,
    const float* __restrict__ topk_w, short* __restrict__ ydown,
    float* __restrict__ out)
{
    const int e = blockIdx.y;
    const int cnt = counts[e];
    const int m_base = blockIdx.z * DM;
    if (m_base >= cnt) return;
    const int n_base = blockIdx.x * DN;

    __shared__ short As[2][DM * KP];
    __shared__ short Bs[2][DN * KP];
    __shared__ int   sl[DM];
    __shared__ float wvs[DM];

    const int tid = threadIdx.x;
    if (tid < DM) {
        int m = m_base + tid;
        int s = (m < cnt) ? slots[e * CAP + m] : -1;
        sl[tid]  = s;
        wvs[tid] = (s >= 0) ? topk_w[s] : 0.f;
    }
    __syncthreads();

    const float* wb = wd + (size_t)e * HH * II;

    // A staging: bf16 hmid, 16B chunks. row = (tid>>2)+64*it, kc = tid&3
    const int kc = tid & 3;
    int rowA[2]; int slA[2]; const short* pAh[2];
    #pragma unroll
    for (int it = 0; it < 2; ++it) {
        rowA[it] = (tid >> 2) + 64 * it;
        int s = sl[rowA[it]];
        slA[it] = s;
        pAh[it] = hmid + (size_t)(s >= 0 ? s : 0) * II + kc * 8;
    }
    // B staging: fp32 wd. row = (tid>>3)+32*it, kq = tid&7
    const int kq = tid & 7;
    int rowB[2]; const float* pB[2];
    #pragma unroll
    for (int it = 0; it < 2; ++it) {
        rowB[it] = (tid >> 3) + 32 * it;
        pB[it] = wb + (size_t)(n_base + rowB[it]) * II + kq * 4;
    }

    const int lane = tid & 63;
    const int wv_  = tid >> 6;
    const int wy   = wv_ & 1;
    const int wx   = wv_ >> 1;
    const int quad = lane >> 4;
    const int mcol = lane & 15;

    floatx4 acc[4][2] = {};

    short8v pa[2]; float4 pb[2];
    const short8v sz = { 0, 0, 0, 0, 0, 0, 0, 0 };

    #pragma unroll
    for (int it = 0; it < 2; ++it) pa[it] = (slA[it] >= 0) ? *(const short8v*)(pAh[it]) : sz;
    #pragma unroll
    for (int it = 0; it < 2; ++it) pb[it] = *(const float4*)(pB[it]);
    #pragma unroll
    for (int it = 0; it < 2; ++it) *(short8v*)&As[0][rowA[it] * KP + kc * 8] = pa[it];
    #pragma unroll
    for (int it = 0; it < 2; ++it) *(short4v*)&Bs[0][rowB[it] * KP + kq * 4] = cvt4(pb[it]);
    __syncthreads();

    int p = 0;
    for (int k0 = 0; k0 < II; k0 += GK) {
        const int kn = k0 + GK;
        const bool more = kn < II;
        if (more) {
            #pragma unroll
            for (int it = 0; it < 2; ++it) pa[it] = (slA[it] >= 0) ? *(const short8v*)(pAh[it] + kn) : sz;
            #pragma unroll
            for (int it = 0; it < 2; ++it) pb[it] = *(const float4*)(pB[it] + kn);
        }

        short8v a[4], b[2];
        #pragma unroll
        for (int i = 0; i < 4; ++i)
            a[i] = *(const short8v*)&As[p][(wy * 64 + i * 16 + mcol) * KP + quad * 8];
        #pragma unroll
        for (int j = 0; j < 2; ++j)
            b[j] = *(const short8v*)&Bs[p][(wx * 32 + j * 16 + mcol) * KP + quad * 8];
        #pragma unroll
        for (int i = 0; i < 4; ++i)
            #pragma unroll
            for (int j = 0; j < 2; ++j)
                acc[i][j] = __builtin_amdgcn_mfma_f32_16x16x32_bf16(a[i], b[j], acc[i][j], 0, 0, 0);

        if (more) {
            #pragma unroll
            for (int it = 0; it < 2; ++it) *(short8v*)&As[1 - p][rowA[it] * KP + kc * 8] = pa[it];
            #pragma unroll
            for (int it = 0; it < 2; ++it) *(short4v*)&Bs[1 - p][rowB[it] * KP + kq * 4] = cvt4(pb[it]);
        }
        __syncthreads();
        p ^= 1;
    }

    #pragma unroll
    for (int i = 0; i < 4; ++i) {
        #pragma unroll
        for (int r = 0; r < 4; ++r) {
            int m = wy * 64 + i * 16 + quad * 4 + r;
            int s = sl[m];
            if (s < 0) continue;
            if (WRITE_Y) {
                short* yrow = ydown + (size_t)s * HH + n_base + wx * 32;
                #pragma unroll
                for (int j = 0; j < 2; ++j)
                    yrow[j * 16 + mcol] = f2bf(acc[i][j][r]);
            } else {
                float w = wvs[m];
                float* orow = out + (size_t)(s >> 2) * HH + n_base + wx * 32;
                #pragma unroll
                for (int j = 0; j < 2; ++j)
                    atomicAdd(&orow[j * 16 + mcol], w * acc[i][j][r]);
            }
        }
    }
}

// ============== Kernel 4a: combine (ydown path) ==============
__global__ __launch_bounds__(256) void combine_kernel(
    const float* __restrict__ x, const short* __restrict__ ydown,
    const float* __restrict__ topk_w, const int* __restrict__ kexp,
    const float* __restrict__ zero_w, float* __restrict__ out)
{
    const int t = blockIdx.x;
    const int c = threadIdx.x;   // float4 index
    const float4 xv = ((const float4*)(x + (size_t)t * HH))[c];
    const float zw = zero_w[t];
    float4 o;
    o.x = zw * xv.x; o.y = zw * xv.y; o.z = zw * xv.z; o.w = zw * xv.w;
    #pragma unroll
    for (int k = 0; k < TOPK; ++k) {
        int slot = t * TOPK + k;
        if (kexp[slot] < EE) {
            float w = topk_w[slot];
            short4v y = *(const short4v*)&ydown[(size_t)slot * HH + c * 4];
            o.x += w * bf2f(y[0]);
            o.y += w * bf2f(y[1]);
            o.z += w * bf2f(y[2]);
            o.w += w * bf2f(y[3]);
        }
    }
    ((float4*)(out + (size_t)t * HH))[c] = o;
}

// ============== Kernel 4b: zero-expert residual (atomic fallback path) ==============
__global__ __launch_bounds__(256) void zero_resid_kernel(
    const float* __restrict__ x, const float* __restrict__ zero_w,
    float* __restrict__ out)
{
    const int t = blockIdx.x;
    const float zw = zero_w[t];
    const int tid = threadIdx.x;
    const float4 xv = ((const float4*)(x + (size_t)t * HH))[tid];
    float4* o = (float4*)(out + (size_t)t * HH);
    float4 ov = o[tid];
    ov.x += zw * xv.x; ov.y += zw * xv.y; ov.z += zw * xv.z; ov.w += zw * xv.w;
    o[tid] = ov;
}

extern "C" void kernel_launch(void* const* d_in, const int* in_sizes, int n_in,
                              void* d_out, int out_size, void* d_ws, size_t ws_size,
                              hipStream_t stream) {
    const float* x    = (const float*)d_in[0];
    const float* rw   = (const float*)d_in[1];
    const float* bias = (const float*)d_in[2];
    const float* wgu  = (const float*)d_in[3];
    const float* wd   = (const float*)d_in[4];
    float* out = (float*)d_out;

    char* ws = (char*)d_ws;
    int*   counts = (int*)ws;
    float* topk_w = (float*)(ws + 1024);
    float* zero_w = (float*)(ws + 17408);
    int*   kexp   = (int*)(ws + 21504);
    int*   slots  = (int*)(ws + 40960);
    short* hmid   = (short*)(ws + 262144);
    short* ydown  = (short*)(ws + 4456448);

    const bool big = ws_size >= WS_NEED_COMBINE;

    hipMemsetAsync(counts, 0, EE * sizeof(int), stream);
    if (!big) hipMemsetAsync(out, 0, (size_t)out_size * sizeof(float), stream);

    router_kernel<<<dim3(TT), dim3(64), 0, stream>>>(
        x, rw, bias, topk_w, zero_w, kexp, counts, slots);
    gate_up_kernel<<<dim3(II / GNP, EE, CAP / GM), dim3(256), 0, stream>>>(
        x, wgu, counts, slots, hmid);
    if (big) {
        down_kernel_t<1><<<dim3(HH / DN, EE, CAP / DM), dim3(256), 0, stream>>>(
            hmid, wd, counts, slots, topk_w, ydown, out);
        combine_kernel<<<dim3(TT), dim3(256), 0, stream>>>(
            x, ydown, topk_w, kexp, zero_w, out);
    } else {
        down_kernel_t<0><<<dim3(HH / DN, EE, CAP / DM), dim3(256), 0, stream>>>(
            hmid, wd, counts, slots, topk_w, nullptr, out);
        zero_resid_kernel<<<dim3(TT), dim3(256), 0, stream>>>(x, zero_w, out);
    }
}